// Round 5
// baseline (705.835 us; speedup 1.0000x reference)
//
#include <hip/hip_runtime.h>

// B=8, C=128, H=96, W=96, D=4
// act: [b][d][h][w][kappa] bf16, kappa-permuted channels, scans IN PLACE.
// Scan kernels: 4 waves per chain (1 chain per 256-thread block):
//   wave 0 = C0 (consumer, channels 0..63, owns B-frags kt 0,1)
//   wave 1 = C1 (consumer, channels 64..127, owns B-frags kt 2,3)
//   wave 2 = P0 (producer, ff half 0 -> f32 LDS ring)
//   wave 3 = P1 (producer, ff half 1 -> f32 LDS ring)
// Consumers exchange their half of the packed bf16 state via a 2-slot LDS
// ring with monotone flag handshakes (no barriers). Critical path per step =
// 16 MFMA (solo-wave ~40cy/MFMA) + LDS latency, vs 32 MFMA in round 3.

typedef short bf16x8 __attribute__((ext_vector_type(8)));
typedef float f32x4 __attribute__((ext_vector_type(4)));
typedef unsigned int uint4v __attribute__((ext_vector_type(4)));

__device__ __forceinline__ unsigned short f2bf(float f) {
  unsigned int u = __builtin_bit_cast(unsigned int, f);
  u = (u + 0x7FFFu + ((u >> 16) & 1u)) >> 16;
  return (unsigned short)u;
}
__device__ __forceinline__ float bf2f(unsigned short h) {
  unsigned int u = ((unsigned int)h) << 16;
  return __builtin_bit_cast(float, u);
}

// kappa = kt*32 + q*8 + j  ->  true channel c = kt*32 + (j>>2)*16 + q*4 + (j&3)
__device__ __forceinline__ int sigma_k(int kap) {
  int kt = kap >> 5, q = (kap >> 3) & 3, j = kap & 7;
  return kt * 32 + ((j >> 2) << 4) + q * 4 + (j & 3);
}

// ---------------- prep ----------------
__global__ __launch_bounds__(256) void prep_kernel(
    const float* __restrict__ W1, const float* __restrict__ b1,
    const float* __restrict__ W2, const float* __restrict__ b2,
    const float* __restrict__ W4, const float* __restrict__ b4,
    const float* __restrict__ W5, const float* __restrict__ b5,
    unsigned short* __restrict__ Wb, float* __restrict__ bs12,
    float* __restrict__ bs45) {
  int gid = blockIdx.x * 256 + threadIdx.x;
  if (gid < 4 * 65536) {
    int m = gid >> 16;
    int r = gid & 65535;          // d*16384 + rho*128 + kappa
    int kap = r & 127;
    int c = sigma_k(kap);
    const float* src = (m == 0) ? W1 : (m == 1) ? W2 : (m == 2) ? W4 : W5;
    Wb[m * 65536 + r] = f2bf(src[(r >> 7) * 128 + c]);
  } else if (gid < 4 * 65536 + 512) {
    int r = gid - 4 * 65536;
    bs12[r] = b1[r] + b2[r];
  } else if (gid < 4 * 65536 + 1024) {
    int r = gid - 4 * 65536 - 512;
    bs45[r] = b4[r] + b5[r];
  }
}

// ---------------- transpose x -> act ----------------
__global__ __launch_bounds__(256) void transpose_kernel(
    const float* __restrict__ x, unsigned short* __restrict__ act) {
  __shared__ unsigned short tile[128 * 208];
  int bid = blockIdx.x;
  int half = bid & 1;
  int rest = bid >> 1;
  int h = rest % 96;
  int b = rest / 96;
  int wd0 = half * 192;
  int tid = threadIdx.x;
#pragma unroll
  for (int it = 0; it < 12; ++it) {
    int cid = it * 256 + tid;
    int c = cid / 24;
    int k = cid % 24;
    const float* xp = x + ((size_t)(b * 128 + c) * 96 + h) * 384 + wd0 + k * 8;
    float4 v0 = *(const float4*)xp;
    float4 v1 = *(const float4*)(xp + 4);
    bf16x8 pk;
    pk[0] = (short)f2bf(v0.x); pk[1] = (short)f2bf(v0.y);
    pk[2] = (short)f2bf(v0.z); pk[3] = (short)f2bf(v0.w);
    pk[4] = (short)f2bf(v1.x); pk[5] = (short)f2bf(v1.y);
    pk[6] = (short)f2bf(v1.z); pk[7] = (short)f2bf(v1.w);
    int ks = k ^ ((c >> 3) & 7);
    *(bf16x8*)&tile[c * 208 + ks * 8] = pk;
  }
  __syncthreads();
#pragma unroll
  for (int it = 0; it < 12; ++it) {
    int sid = it * 256 + tid;
    int wdl = sid >> 4;
    int cc = sid & 15;              // kappa0 = cc*8
    int k = wdl >> 3, off = wdl & 7;
    int ktq = cc >> 2, qq = cc & 3;
    bf16x8 pk;
#pragma unroll
    for (int j = 0; j < 8; ++j) {
      int c = ktq * 32 + ((j >> 2) << 4) + qq * 4 + (j & 3);
      int ks = k ^ ((c >> 3) & 7);
      pk[j] = (short)tile[c * 208 + ks * 8 + off];
    }
    int wdg = wd0 + wdl;
    int d = wdg & 3, w = wdg >> 2;
    *(bf16x8*)(act + ((((size_t)(b * 4 + d) * 96 + h) * 96 + w) * 128 + cc * 8)) = pk;
  }
}

// Flag indices in flg[i][0]: 0,1=pw (producer wrote) 2,3=pc (slot consumed)
// 4,5=xw (frags written) 6,7=xr (partner frags read)
#define FPW(s) F[(0 + (s)) * 16]
#define FPC(s) F[(2 + (s)) * 16]
#define FXW(s) F[(4 + (s)) * 16]
#define FXR(s) F[(6 + (s)) * 16]

// Shared scan body. STRIDE = elements between successive scan positions.
// SEED_RELU: apply bf16 relu to the seed (col scan) and write seed to output.
template <int STRIDE, bool SEED_RELU>
__device__ __forceinline__ void scan_body(
    unsigned short* act, const unsigned short* wfp, const unsigned short* wrp,
    const float* bsum, size_t base, int d) {
  __shared__ float pslot[2][2][4][64][4];          // [s][ring][mi][lane][4] 16KB
  __shared__ unsigned short xpart[2][2][2][512];   // [ring][s][ktl][lane*8] 8KB
  __shared__ int flg[8][16];
  volatile int* F = &flg[0][0];
  int tid = threadIdx.x;
  int wv = tid >> 6;
  int lane = tid & 63;
  int q = lane >> 4, n = lane & 15;
  int s = wv & 1;

  if (tid < 8) flg[tid][0] = (tid >= 6) ? -1 : 0;

  const unsigned short* inp = act + base;   // position t at + t*STRIDE

  if (wv >= 2) {
    // ================= producer s =================
    bf16x8 A1[4][4];
#pragma unroll
    for (int mi = 0; mi < 4; ++mi) {
      int c = (4 * s + mi) * 16 + n;
#pragma unroll
      for (int kt = 0; kt < 4; ++kt)
        A1[mi][kt] = *(const bf16x8*)(wfp + c * 128 + kt * 32 + q * 8);
    }
    f32x4 bias[4];
#pragma unroll
    for (int mi = 0; mi < 4; ++mi)
#pragma unroll
      for (int r = 0; r < 4; ++r)
        bias[mi][r] = bsum[d * 128 + (4 * s + mi) * 16 + q * 4 + r];
    bf16x8 Bn[4], Bf[4];
    // invariant at entry t: Bn = input t, Bf = input t+1
#pragma unroll
    for (int kt = 0; kt < 4; ++kt) {
      Bn[kt] = *(const bf16x8*)(inp + (size_t)1 * STRIDE + kt * 32);
      Bf[kt] = *(const bf16x8*)(inp + (size_t)2 * STRIDE + kt * 32);
    }
    __syncthreads();
#pragma unroll 1
    for (int t = 1; t <= 95; ++t) {
      while (t - FPC(s) > 2) {}
      asm volatile("" ::: "memory");
      f32x4 acc[4];
#pragma unroll
      for (int mi = 0; mi < 4; ++mi)
        acc[mi] = __builtin_amdgcn_mfma_f32_16x16x32_bf16(A1[mi][0], Bn[0],
                                                          bias[mi], 0, 0, 0);
#pragma unroll
      for (int kt = 1; kt < 4; ++kt)
#pragma unroll
        for (int mi = 0; mi < 4; ++mi)
          acc[mi] = __builtin_amdgcn_mfma_f32_16x16x32_bf16(A1[mi][kt], Bn[kt],
                                                            acc[mi], 0, 0, 0);
      int tp = (t + 2 <= 95) ? t + 2 : 95;
      const unsigned short* pf = inp + (size_t)tp * STRIDE;
#pragma unroll
      for (int kt = 0; kt < 4; ++kt) {
        Bn[kt] = Bf[kt];
        Bf[kt] = *(const bf16x8*)(pf + kt * 32);
      }
      float* sp = &pslot[s][t & 1][0][lane][0];
#pragma unroll
      for (int mi = 0; mi < 4; ++mi)
        *(f32x4*)(sp + mi * 256) = acc[mi];
      asm volatile("s_waitcnt lgkmcnt(0)" ::: "memory");
      if (lane == 0) FPW(s) = t;
    }
  } else {
    // ================= consumer s =================
    bf16x8 A2[4][4];
#pragma unroll
    for (int mi = 0; mi < 4; ++mi) {
      int c = (4 * s + mi) * 16 + n;
#pragma unroll
      for (int kt = 0; kt < 4; ++kt)
        A2[mi][kt] = *(const bf16x8*)(wrp + c * 128 + kt * 32 + q * 8);
    }
    unsigned short* outp = act + base;
    bf16x8 Bo[2];  // own frags, global kt = 2s+ktl
#pragma unroll
    for (int ktl = 0; ktl < 2; ++ktl) {
      bf16x8 v = *(const bf16x8*)(inp + (2 * s + ktl) * 32);
      if (SEED_RELU) {
#pragma unroll
        for (int j = 0; j < 8; ++j) {
          unsigned short uv = (unsigned short)v[j];
          if (uv & 0x8000u) v[j] = 0;  // bf16 relu
        }
        *(bf16x8*)(outp + (2 * s + ktl) * 32) = v;  // seed output in place
      }
      Bo[ktl] = v;
      *(bf16x8*)&xpart[0][s][ktl][lane * 8] = v;  // publish step-0 frags
    }
    if (SEED_RELU) outp += STRIDE;      // col: outputs start at t=0 (done)
    else outp += STRIDE;                // row: outputs start at t=1
    __syncthreads();
#pragma unroll 1
    for (int t = 1; t <= 95; ++t) {
      // partner frags from step t-1
      while (FXW(1 - s) < t - 1) {}
      asm volatile("" ::: "memory");
      const unsigned short* xp0 = &xpart[(t - 1) & 1][1 - s][0][lane * 8];
      bf16x8 Bq0 = *(const bf16x8*)xp0;
      bf16x8 Bq1 = *(const bf16x8*)(xp0 + 512);
      // ff half from producer
      while (FPW(s) < t) {}
      asm volatile("" ::: "memory");
      const float* sp = &pslot[s][t & 1][0][lane][0];
      f32x4 acc[4];
#pragma unroll
      for (int mi = 0; mi < 4; ++mi)
        acc[mi] = *(const f32x4*)(sp + mi * 256);
      asm volatile("s_waitcnt lgkmcnt(0)" ::: "memory");
      if (lane == 0) { FPC(s) = t; FXR(s) = t - 1; }
      // 16 MFMA: own frags first (global kt 2s+ktl), then partner's
#pragma unroll
      for (int ktl = 0; ktl < 2; ++ktl)
#pragma unroll
        for (int mi = 0; mi < 4; ++mi)
          acc[mi] = __builtin_amdgcn_mfma_f32_16x16x32_bf16(
              A2[mi][2 * s + ktl], Bo[ktl], acc[mi], 0, 0, 0);
#pragma unroll
      for (int mi = 0; mi < 4; ++mi)
        acc[mi] = __builtin_amdgcn_mfma_f32_16x16x32_bf16(
            A2[mi][2 * (1 - s) + 0], Bq0, acc[mi], 0, 0, 0);
#pragma unroll
      for (int mi = 0; mi < 4; ++mi)
        acc[mi] = __builtin_amdgcn_mfma_f32_16x16x32_bf16(
            A2[mi][2 * (1 - s) + 1], Bq1, acc[mi], 0, 0, 0);
      // relu + pack own 2 frags, store
#pragma unroll
      for (int ktl = 0; ktl < 2; ++ktl) {
        unsigned int u0, u1, u2, u3;
        float a0 = fmaxf(acc[2 * ktl][0], 0.f);
        float a1 = fmaxf(acc[2 * ktl][1], 0.f);
        float a2 = fmaxf(acc[2 * ktl][2], 0.f);
        float a3 = fmaxf(acc[2 * ktl][3], 0.f);
        float c0 = fmaxf(acc[2 * ktl + 1][0], 0.f);
        float c1 = fmaxf(acc[2 * ktl + 1][1], 0.f);
        float c2 = fmaxf(acc[2 * ktl + 1][2], 0.f);
        float c3 = fmaxf(acc[2 * ktl + 1][3], 0.f);
        asm("v_cvt_pk_bf16_f32 %0, %1, %2" : "=v"(u0) : "v"(a0), "v"(a1));
        asm("v_cvt_pk_bf16_f32 %0, %1, %2" : "=v"(u1) : "v"(a2), "v"(a3));
        asm("v_cvt_pk_bf16_f32 %0, %1, %2" : "=v"(u2) : "v"(c0), "v"(c1));
        asm("v_cvt_pk_bf16_f32 %0, %1, %2" : "=v"(u3) : "v"(c2), "v"(c3));
        uint4v uu;
        uu[0] = u0; uu[1] = u1; uu[2] = u2; uu[3] = u3;
        Bo[ktl] = __builtin_bit_cast(bf16x8, uu);
        *(bf16x8*)(outp + (2 * s + ktl) * 32) = Bo[ktl];
      }
      outp += STRIDE;
      // publish own frags for partner's step t+1
      while (FXR(1 - s) < t - 2) {}
      asm volatile("" ::: "memory");
      unsigned short* xw = &xpart[t & 1][s][0][lane * 8];
      *(bf16x8*)xw = Bo[0];
      *(bf16x8*)(xw + 512) = Bo[1];
      asm volatile("s_waitcnt lgkmcnt(0)" ::: "memory");
      if (lane == 0) FXW(s) = t;
    }
  }
}

// ---------------- row scan ----------------
__global__ __launch_bounds__(256, 1) void row_kernel(
    unsigned short* act, const unsigned short* __restrict__ Wb,
    const float* __restrict__ bs12) {
  int bid = blockIdx.x;
  int wt = bid % 6;
  int bd = bid / 6;  // b*4+d
  int d = bd & 3;
  int w0 = wt * 16;
  int lane = threadIdx.x & 63;
  int q = lane >> 4, n = lane & 15;
  size_t base = ((size_t)bd * 9216 + (size_t)(w0 + n)) * 128 + q * 8;
  scan_body<12288, false>(act, Wb + d * 16384, Wb + 65536 + d * 16384, bs12,
                          base, d);
}

// ---------------- col scan ----------------
__global__ __launch_bounds__(256, 1) void col_kernel(
    unsigned short* act, const unsigned short* __restrict__ Wb,
    const float* __restrict__ bs45) {
  int bid = blockIdx.x;
  int ht = bid % 6;
  int bd = bid / 6;
  int d = bd & 3;
  int h0 = ht * 16;
  int lane = threadIdx.x & 63;
  int q = lane >> 4, n = lane & 15;
  size_t base = ((size_t)bd * 9216 + (size_t)(h0 + n) * 96) * 128 + q * 8;
  scan_body<128, true>(act, Wb + 2 * 65536 + d * 16384,
                       Wb + 3 * 65536 + d * 16384, bs45, base, d);
}

// ---------------- out = x + unpermute(act) ----------------
__global__ __launch_bounds__(256) void out_kernel(
    const float* __restrict__ x, const unsigned short* __restrict__ act,
    float* __restrict__ out) {
  __shared__ unsigned short tile[128 * 208];
  int bid = blockIdx.x;
  int half = bid & 1;
  int rest = bid >> 1;
  int h = rest % 96;
  int b = rest / 96;
  int wd0 = half * 192;
  int tid = threadIdx.x;
#pragma unroll
  for (int it = 0; it < 12; ++it) {
    int gid = it * 256 + tid;
    int wdl = gid >> 4;
    int cc = gid & 15;              // kappa0 = cc*8
    int wdg = wd0 + wdl;
    int d = wdg & 3, w = wdg >> 2;
    bf16x8 v = *(const bf16x8*)(
        act + ((((size_t)(b * 4 + d) * 96 + h) * 96 + w) * 128 + cc * 8));
    int k = wdl >> 3, off = wdl & 7;
    int ktq = cc >> 2, qq = cc & 3;
#pragma unroll
    for (int j = 0; j < 8; ++j) {
      int c = ktq * 32 + ((j >> 2) << 4) + qq * 4 + (j & 3);
      int ks = k ^ ((c >> 3) & 7);
      tile[c * 208 + ks * 8 + off] = (unsigned short)v[j];
    }
  }
  __syncthreads();
#pragma unroll
  for (int it = 0; it < 12; ++it) {
    int sid = it * 256 + tid;
    int c = sid / 24;
    int k = sid % 24;
    int ks = k ^ ((c >> 3) & 7);
    bf16x8 pk = *(const bf16x8*)&tile[c * 208 + ks * 8];
    size_t o = ((size_t)(b * 128 + c) * 96 + h) * 384 + wd0 + k * 8;
    float4 a0 = *(const float4*)(x + o);
    float4 a1 = *(const float4*)(x + o + 4);
    float4 r0, r1;
    r0.x = a0.x + bf2f((unsigned short)pk[0]);
    r0.y = a0.y + bf2f((unsigned short)pk[1]);
    r0.z = a0.z + bf2f((unsigned short)pk[2]);
    r0.w = a0.w + bf2f((unsigned short)pk[3]);
    r1.x = a1.x + bf2f((unsigned short)pk[4]);
    r1.y = a1.y + bf2f((unsigned short)pk[5]);
    r1.z = a1.z + bf2f((unsigned short)pk[6]);
    r1.w = a1.w + bf2f((unsigned short)pk[7]);
    *(float4*)(out + o) = r0;
    *(float4*)(out + o + 4) = r1;
  }
}

extern "C" void kernel_launch(void* const* d_in, const int* in_sizes, int n_in,
                              void* d_out, int out_size, void* d_ws,
                              size_t ws_size, hipStream_t stream) {
  (void)in_sizes; (void)n_in; (void)out_size; (void)ws_size;
  const float* x  = (const float*)d_in[0];
  const float* W1 = (const float*)d_in[1];
  const float* b1 = (const float*)d_in[2];
  const float* W2 = (const float*)d_in[3];
  const float* b2 = (const float*)d_in[4];
  const float* W4 = (const float*)d_in[5];
  const float* b4 = (const float*)d_in[6];
  const float* W5 = (const float*)d_in[7];
  const float* b5 = (const float*)d_in[8];
  float* out = (float*)d_out;

  char* ws = (char*)d_ws;
  unsigned short* Wb  = (unsigned short*)(ws);            // 524288 B
  float* bs12         = (float*)(ws + 524288);            // 2048 B
  float* bs45         = (float*)(ws + 526336);            // 2048 B
  unsigned short* act = (unsigned short*)(ws + 528384);   // 75497472 B

  prep_kernel<<<(4 * 65536 + 1024 + 255) / 256, 256, 0, stream>>>(
      W1, b1, W2, b2, W4, b4, W5, b5, Wb, bs12, bs45);
  transpose_kernel<<<8 * 96 * 2, 256, 0, stream>>>(x, act);
  row_kernel<<<192, 256, 0, stream>>>(act, Wb, bs12);
  col_kernel<<<192, 256, 0, stream>>>(act, Wb, bs45);
  out_kernel<<<8 * 96 * 2, 256, 0, stream>>>(x, act, out);
}